// Round 1
// baseline (646.243 us; speedup 1.0000x reference)
//
#include <hip/hip_runtime.h>
#include <hip/hip_bf16.h>
#include <math.h>

// Problem constants (from reference)
#define B_IMG   8
#define C_IN    1024
#define HW      64          // H = W = 64
#define N_BOX   64
#define R_ROI   (B_IMG * N_BOX)   // 512
#define POOL    4
#define SR      2
#define C1      256
#define C2      128
#define OUT_DIM 2048
#define M1      (R_ROI * POOL * POOL)   // 8192 rows for gemm1/2

// ---------------------------------------------------------------------------
// Kernel 1: ROI align -> pooled (8192 x 1024) row-major, row = r*16 + (py*4+px)
// ---------------------------------------------------------------------------
__global__ __launch_bounds__(256) void roi_align_kernel(
    const float* __restrict__ feat,    // (8,1024,64,64)
    const float* __restrict__ boxes,   // (8,64,4)
    const float* __restrict__ scale_p, // (1,)
    float* __restrict__ pooled)        // (8192,1024)
{
    const int r = blockIdx.x;          // 0..511
    const int tid = threadIdx.x;

    __shared__ int   s_ylo[8], s_yhi[8], s_xlo[8], s_xhi[8];
    __shared__ float s_ly[8], s_lx[8];
    __shared__ int   s_vy[8], s_vx[8];

    if (tid < 16) {
        const int axis = tid >> 3;     // 0 = y, 1 = x
        const int j    = tid & 7;
        const float s  = scale_p[0];
        const float bx1 = boxes[r*4 + 0] * s;
        const float by1 = boxes[r*4 + 1] * s;
        const float bx2 = boxes[r*4 + 2] * s;
        const float by2 = boxes[r*4 + 3] * s;
        const float start = axis ? bx1 : by1;
        const float end   = axis ? bx2 : by2;
        const float sz  = fmaxf(end - start, 1.0f);
        const float bin = sz * 0.25f;                       // size / POOL
        const float off = (float)(j >> 1) + (float)(j & 1) * 0.5f + 0.25f;
        float c = start + off * bin;
        const int v = (c >= -1.0f && c <= 64.0f) ? 1 : 0;
        c = fminf(fmaxf(c, 0.0f), 63.0f);
        int lo = (int)floorf(c);
        if (lo > 63) lo = 63;
        int hi = lo + 1; if (hi > 63) hi = 63;
        const float fr = c - (float)lo;
        if (axis == 0) { s_ylo[j] = lo; s_yhi[j] = hi; s_ly[j] = fr; s_vy[j] = v; }
        else           { s_xlo[j] = lo; s_xhi[j] = hi; s_lx[j] = fr; s_vx[j] = v; }
    }
    __syncthreads();

    const int b = r >> 6;                                   // r / 64
    const float* base0 = feat + (size_t)b * C_IN * (HW * HW);

    for (int c = tid; c < C_IN; c += 256) {
        const float* fb = base0 + (size_t)c * (HW * HW);
        float acc[16];
        #pragma unroll
        for (int p = 0; p < 16; ++p) acc[p] = 0.0f;

        #pragma unroll
        for (int jy = 0; jy < 8; ++jy) {
            const int   ylo = s_ylo[jy], yhi = s_yhi[jy];
            const float ly  = s_ly[jy];
            const float hy  = 1.0f - ly;
            const int   vy  = s_vy[jy];
            const float* rlo = fb + ylo * HW;
            const float* rhi = fb + yhi * HW;
            #pragma unroll
            for (int jx = 0; jx < 8; ++jx) {
                float val = 0.0f;
                if (vy && s_vx[jx]) {
                    const float lx = s_lx[jx];
                    const float hx = 1.0f - lx;
                    const int xlo = s_xlo[jx], xhi = s_xhi[jx];
                    const float v00 = rlo[xlo], v01 = rlo[xhi];
                    const float v10 = rhi[xlo], v11 = rhi[xhi];
                    val = v00 * hy * hx + v01 * hy * lx + v10 * ly * hx + v11 * ly * lx;
                }
                acc[(jy >> 1) * 4 + (jx >> 1)] += val;
            }
        }

        float* outp = pooled + (size_t)r * 16 * C_IN + c;
        #pragma unroll
        for (int p = 0; p < 16; ++p) outp[(size_t)p * C_IN] = acc[p] * 0.25f;
    }
}

// ---------------------------------------------------------------------------
// Kernel 2: NT GEMM (A: MxK row-major, B(weights): NxK row-major) + bias + ELU.
// BM=BN=64, BK=16, 256 threads, 4x4 per thread.
// SCATTER: write C[r*2048 + n*16 + p] where m = r*16+p (gemm2 flatten layout).
// ---------------------------------------------------------------------------
template<bool SCATTER>
__global__ __launch_bounds__(256) void gemm_nt_bias_elu(
    const float* __restrict__ A, const float* __restrict__ B,
    const float* __restrict__ bias, float* __restrict__ C,
    int M, int N, int K)
{
    constexpr int BM = 64, BN = 64, BK = 16, PAD = 4;
    __shared__ __align__(16) float As[BK][BM + PAD];
    __shared__ __align__(16) float Bs[BK][BN + PAD];

    const int tid = threadIdx.x;
    const int ty = tid >> 4;          // 0..15
    const int tx = tid & 15;          // 0..15
    const int m0 = blockIdx.x * BM;
    const int n0 = blockIdx.y * BN;

    // loader mapping: each thread loads one float4 of A and one of B
    const int lr = tid >> 2;          // row within tile 0..63
    const int lk = (tid & 3) * 4;     // k offset within tile 0..12

    float acc[4][4];
    #pragma unroll
    for (int i = 0; i < 4; ++i)
        #pragma unroll
        for (int j = 0; j < 4; ++j) acc[i][j] = 0.0f;

    for (int k0 = 0; k0 < K; k0 += BK) {
        const float4 av = *reinterpret_cast<const float4*>(&A[(size_t)(m0 + lr) * K + k0 + lk]);
        const float4 bv = *reinterpret_cast<const float4*>(&B[(size_t)(n0 + lr) * K + k0 + lk]);
        As[lk + 0][lr] = av.x; As[lk + 1][lr] = av.y; As[lk + 2][lr] = av.z; As[lk + 3][lr] = av.w;
        Bs[lk + 0][lr] = bv.x; Bs[lk + 1][lr] = bv.y; Bs[lk + 2][lr] = bv.z; Bs[lk + 3][lr] = bv.w;
        __syncthreads();

        #pragma unroll
        for (int k = 0; k < BK; ++k) {
            const float4 a4 = *reinterpret_cast<const float4*>(&As[k][ty * 4]);
            const float4 b4 = *reinterpret_cast<const float4*>(&Bs[k][tx * 4]);
            const float aa[4] = {a4.x, a4.y, a4.z, a4.w};
            const float bb[4] = {b4.x, b4.y, b4.z, b4.w};
            #pragma unroll
            for (int i = 0; i < 4; ++i)
                #pragma unroll
                for (int j = 0; j < 4; ++j) acc[i][j] += aa[i] * bb[j];
        }
        __syncthreads();
    }

    #pragma unroll
    for (int i = 0; i < 4; ++i) {
        const int m = m0 + ty * 4 + i;
        #pragma unroll
        for (int j = 0; j < 4; ++j) {
            const int n = n0 + tx * 4 + j;
            float v = acc[i][j] + bias[n];
            v = (v > 0.0f) ? v : (expf(v) - 1.0f);
            if (!SCATTER) {
                C[(size_t)m * N + n] = v;
            } else {
                const int r = m >> 4;
                const int p = m & 15;
                C[(size_t)r * 2048 + n * 16 + p] = v;
            }
        }
    }
}

// ---------------------------------------------------------------------------
extern "C" void kernel_launch(void* const* d_in, const int* in_sizes, int n_in,
                              void* d_out, int out_size, void* d_ws, size_t ws_size,
                              hipStream_t stream) {
    const float* x     = (const float*)d_in[0];
    const float* boxes = (const float*)d_in[1];
    const float* scale = (const float*)d_in[2];
    const float* w1    = (const float*)d_in[3];
    const float* b1    = (const float*)d_in[4];
    const float* w2    = (const float*)d_in[5];
    const float* b2    = (const float*)d_in[6];
    const float* wl    = (const float*)d_in[7];
    const float* bl    = (const float*)d_in[8];
    float* out = (float*)d_out;

    // workspace layout (fp32)
    float* pooled = (float*)d_ws;                                     // 8192 x 1024 = 33.55 MB
    float* h1     = pooled + (size_t)M1 * C_IN;                       // 8192 x 256  =  8.39 MB
    float* h2     = h1 + (size_t)M1 * C1;                             //  512 x 2048 =  4.19 MB

    // 1) ROI align
    roi_align_kernel<<<dim3(R_ROI), dim3(256), 0, stream>>>(x, boxes, scale, pooled);

    // 2) gemm1: (8192x1024) @ w1^T -> h1 (8192x256), bias+ELU
    gemm_nt_bias_elu<false><<<dim3(M1 / 64, C1 / 64), dim3(256), 0, stream>>>(
        pooled, w1, b1, h1, M1, C1, C_IN);

    // 3) gemm2: (8192x256) @ w2^T -> h2 scatter (512x2048), bias+ELU
    gemm_nt_bias_elu<true><<<dim3(M1 / 64, C2 / 64), dim3(256), 0, stream>>>(
        h1, w2, b2, h2, M1, C2, C1);

    // 4) gemm3: (512x2048) @ wl^T -> out (512x2048), bias+ELU
    gemm_nt_bias_elu<false><<<dim3(R_ROI / 64, OUT_DIM / 64), dim3(256), 0, stream>>>(
        h2, wl, bl, out, R_ROI, OUT_DIM, OUT_DIM);
}

// Round 2
// 118.539 us; speedup vs baseline: 5.4517x; 5.4517x over previous
//
#include <hip/hip_runtime.h>
#include <math.h>

// Problem constants
#define B_IMG   8
#define C_INK   1024
#define HWD     64
#define R_ROI   512
#define C1D     256
#define C2D     128
#define OUTD    2048
#define M1D     8192          // R_ROI*16
#define MPIX    32768         // B*H*W

typedef _Float16 half8 __attribute__((ext_vector_type(8)));
typedef float    f32x4 __attribute__((ext_vector_type(4)));

__device__ __forceinline__ unsigned int pack2h(float a, float b) {
    union { _Float16 h[2]; unsigned int u; } p;
    p.h[0] = (_Float16)a; p.h[1] = (_Float16)b;
    return p.u;
}
__device__ __forceinline__ float eluf(float v) { return v > 0.f ? v : expf(v) - 1.f; }

// ---------------------------------------------------------------------------
// Kernel 1: conv1x1 = TN GEMM. z[m][o] = sum_k x[b][k][p] * w1[o][k]
// m = b*4096 + p (pixel), fp16 output channels-last. BM=BN=128, BK=64.
// ---------------------------------------------------------------------------
__global__ __launch_bounds__(256) void conv1x1_f16(
    const float* __restrict__ x, const float* __restrict__ w1,
    _Float16* __restrict__ z)
{
    __shared__ _Float16 As[128][72];   // [pixel][k]
    __shared__ _Float16 Bs[128][72];   // [ochan][k]

    const int tid  = threadIdx.x;
    const int m0   = blockIdx.x * 128;
    const int n0   = blockIdx.y * 128;
    const int b    = m0 >> 12;
    const int p0   = m0 & 4095;
    const int lane = tid & 63;
    const int wave = tid >> 6;
    const int wr   = wave >> 1, wc = wave & 1;

    f32x4 acc[4][4];
    #pragma unroll
    for (int i = 0; i < 4; ++i)
        #pragma unroll
        for (int j = 0; j < 4; ++j) acc[i][j] = (f32x4){0.f, 0.f, 0.f, 0.f};

    const int kpair = tid >> 3;        // 0..31 -> k = 2*kpair
    const int c8    = tid & 7;
    const int wrow  = tid >> 4;        // 0..15 (for W stage)
    const int wkc   = tid & 15;

    for (int k0 = 0; k0 < C_INK; k0 += 64) {
        // stage A: transpose x[k][p] -> As[p][k], convert to fp16
        const float* xk = x + ((size_t)(b * C_INK + k0 + kpair * 2)) * 4096 + p0;
        #pragma unroll
        for (int i = 0; i < 4; ++i) {
            const int col = (c8 + i * 8) * 4;
            const float4 v0 = *reinterpret_cast<const float4*>(xk + col);
            const float4 v1 = *reinterpret_cast<const float4*>(xk + 4096 + col);
            *reinterpret_cast<unsigned int*>(&As[col + 0][kpair * 2]) = pack2h(v0.x, v1.x);
            *reinterpret_cast<unsigned int*>(&As[col + 1][kpair * 2]) = pack2h(v0.y, v1.y);
            *reinterpret_cast<unsigned int*>(&As[col + 2][kpair * 2]) = pack2h(v0.z, v1.z);
            *reinterpret_cast<unsigned int*>(&As[col + 3][kpair * 2]) = pack2h(v0.w, v1.w);
        }
        // stage B: w1[n][k] convert to fp16 (k contiguous)
        #pragma unroll
        for (int i = 0; i < 8; ++i) {
            const int row = wrow + i * 16;
            const float4 v = *reinterpret_cast<const float4*>(&w1[(size_t)(n0 + row) * C_INK + k0 + wkc * 4]);
            uint2 u; u.x = pack2h(v.x, v.y); u.y = pack2h(v.z, v.w);
            *reinterpret_cast<uint2*>(&Bs[row][wkc * 4]) = u;
        }
        __syncthreads();

        #pragma unroll
        for (int kk = 0; kk < 2; ++kk) {
            const int koff = kk * 32 + (lane >> 4) * 8;
            half8 af[4], bf[4];
            #pragma unroll
            for (int mi = 0; mi < 4; ++mi)
                af[mi] = *reinterpret_cast<const half8*>(&As[wr * 64 + mi * 16 + (lane & 15)][koff]);
            #pragma unroll
            for (int ni = 0; ni < 4; ++ni)
                bf[ni] = *reinterpret_cast<const half8*>(&Bs[wc * 64 + ni * 16 + (lane & 15)][koff]);
            #pragma unroll
            for (int mi = 0; mi < 4; ++mi)
                #pragma unroll
                for (int ni = 0; ni < 4; ++ni)
                    acc[mi][ni] = __builtin_amdgcn_mfma_f32_16x16x32_f16(af[mi], bf[ni], acc[mi][ni], 0, 0, 0);
        }
        __syncthreads();
    }

    #pragma unroll
    for (int mi = 0; mi < 4; ++mi)
        #pragma unroll
        for (int ni = 0; ni < 4; ++ni)
            #pragma unroll
            for (int j = 0; j < 4; ++j) {
                const int row = m0 + wr * 64 + mi * 16 + (lane >> 4) * 4 + j;
                const int col = n0 + wc * 64 + ni * 16 + (lane & 15);
                z[(size_t)row * C1D + col] = (_Float16)acc[mi][ni][j];
            }
}

// ---------------------------------------------------------------------------
// Kernel 2: ROI-align gather on z (channels-last fp16) + bias + ELU -> h1
// one block per ROI, thread = channel (256). h1[(r*16+cell)*256 + c] fp16
// ---------------------------------------------------------------------------
__global__ __launch_bounds__(256) void roi_gather_f16(
    const _Float16* __restrict__ z, const float* __restrict__ boxes,
    const float* __restrict__ scale_p, const float* __restrict__ b1,
    _Float16* __restrict__ h1)
{
    const int r   = blockIdx.x;
    const int tid = threadIdx.x;

    __shared__ int   s_off[64][4];
    __shared__ float s_w[64][4];

    if (tid < 64) {
        const float sc = scale_p[0];
        const float x1 = boxes[r * 4 + 0] * sc, y1 = boxes[r * 4 + 1] * sc;
        const float x2 = boxes[r * 4 + 2] * sc, y2 = boxes[r * 4 + 3] * sc;
        const float rw = fmaxf(x2 - x1, 1.f), rh = fmaxf(y2 - y1, 1.f);
        const int jy = tid >> 3, jx = tid & 7;

        float offy = (float)(jy >> 1) + (float)(jy & 1) * 0.5f + 0.25f;
        float cy = y1 + offy * rh * 0.25f;
        const bool vy = (cy >= -1.f) && (cy <= 64.f);
        cy = fminf(fmaxf(cy, 0.f), 63.f);
        int ylo = (int)cy; if (ylo > 63) ylo = 63;
        int yhi = ylo + 1; if (yhi > 63) yhi = 63;
        const float ly = cy - (float)ylo, hy = 1.f - ly;

        float offx = (float)(jx >> 1) + (float)(jx & 1) * 0.5f + 0.25f;
        float cx = x1 + offx * rw * 0.25f;
        const bool vx = (cx >= -1.f) && (cx <= 64.f);
        cx = fminf(fmaxf(cx, 0.f), 63.f);
        int xlo = (int)cx; if (xlo > 63) xlo = 63;
        int xhi = xlo + 1; if (xhi > 63) xhi = 63;
        const float lx = cx - (float)xlo, hx = 1.f - lx;

        const float wm = (vy && vx) ? 0.25f : 0.f;   // fold the 2x2 mean here
        s_w[tid][0] = hy * hx * wm;
        s_w[tid][1] = hy * lx * wm;
        s_w[tid][2] = ly * hx * wm;
        s_w[tid][3] = ly * lx * wm;
        s_off[tid][0] = (ylo * 64 + xlo) * C1D;
        s_off[tid][1] = (ylo * 64 + xhi) * C1D;
        s_off[tid][2] = (yhi * 64 + xlo) * C1D;
        s_off[tid][3] = (yhi * 64 + xhi) * C1D;
    }
    __syncthreads();

    const _Float16* zb = z + (size_t)(r >> 6) * 4096 * C1D + tid;   // channel = tid
    float acc[16];
    #pragma unroll
    for (int i = 0; i < 16; ++i) acc[i] = 0.f;

    #pragma unroll
    for (int s = 0; s < 64; ++s) {
        const int cell = ((s >> 4) & 3) * 4 + ((s >> 1) & 3);
        const float v0 = (float)zb[s_off[s][0]];
        const float v1 = (float)zb[s_off[s][1]];
        const float v2 = (float)zb[s_off[s][2]];
        const float v3 = (float)zb[s_off[s][3]];
        acc[cell] += v0 * s_w[s][0] + v1 * s_w[s][1] + v2 * s_w[s][2] + v3 * s_w[s][3];
    }

    const float bias = b1[tid];
    _Float16* hp = h1 + (size_t)r * 16 * C1D + tid;
    #pragma unroll
    for (int cell = 0; cell < 16; ++cell)
        hp[(size_t)cell * C1D] = (_Float16)eluf(acc[cell] + bias);
}

// ---------------------------------------------------------------------------
// Kernel 3: NT GEMM, A fp16 (MxK), W fp32 (NxK) converted, bias+ELU.
// OUT_MODE 1: fp16 scatter h2[(m>>4)*2048 + n*16 + (m&15)]
// OUT_MODE 2: fp32 plain  out[m*N + n]
// ---------------------------------------------------------------------------
template<int OUT_MODE>
__global__ __launch_bounds__(256) void gemm_nt_f16(
    const _Float16* __restrict__ A, const float* __restrict__ W,
    const float* __restrict__ bias, void* __restrict__ Cout,
    int M, int N, int K)
{
    __shared__ _Float16 As[128][72];
    __shared__ _Float16 Bs[128][72];

    const int tid  = threadIdx.x;
    const int m0   = blockIdx.x * 128;
    const int n0   = blockIdx.y * 128;
    const int lane = tid & 63;
    const int wave = tid >> 6;
    const int wr   = wave >> 1, wc = wave & 1;
    const int srow = tid >> 4;     // 0..15
    const int skc  = tid & 15;     // 0..15

    f32x4 acc[4][4];
    #pragma unroll
    for (int i = 0; i < 4; ++i)
        #pragma unroll
        for (int j = 0; j < 4; ++j) acc[i][j] = (f32x4){0.f, 0.f, 0.f, 0.f};

    for (int k0 = 0; k0 < K; k0 += 64) {
        #pragma unroll
        for (int i = 0; i < 8; ++i) {
            const int row = srow + i * 16;
            const uint2 v = *reinterpret_cast<const uint2*>(&A[(size_t)(m0 + row) * K + k0 + skc * 4]);
            *reinterpret_cast<uint2*>(&As[row][skc * 4]) = v;
            const float4 w = *reinterpret_cast<const float4*>(&W[(size_t)(n0 + row) * K + k0 + skc * 4]);
            uint2 u; u.x = pack2h(w.x, w.y); u.y = pack2h(w.z, w.w);
            *reinterpret_cast<uint2*>(&Bs[row][skc * 4]) = u;
        }
        __syncthreads();

        #pragma unroll
        for (int kk = 0; kk < 2; ++kk) {
            const int koff = kk * 32 + (lane >> 4) * 8;
            half8 af[4], bf[4];
            #pragma unroll
            for (int mi = 0; mi < 4; ++mi)
                af[mi] = *reinterpret_cast<const half8*>(&As[wr * 64 + mi * 16 + (lane & 15)][koff]);
            #pragma unroll
            for (int ni = 0; ni < 4; ++ni)
                bf[ni] = *reinterpret_cast<const half8*>(&Bs[wc * 64 + ni * 16 + (lane & 15)][koff]);
            #pragma unroll
            for (int mi = 0; mi < 4; ++mi)
                #pragma unroll
                for (int ni = 0; ni < 4; ++ni)
                    acc[mi][ni] = __builtin_amdgcn_mfma_f32_16x16x32_f16(af[mi], bf[ni], acc[mi][ni], 0, 0, 0);
        }
        __syncthreads();
    }

    #pragma unroll
    for (int mi = 0; mi < 4; ++mi)
        #pragma unroll
        for (int ni = 0; ni < 4; ++ni)
            #pragma unroll
            for (int j = 0; j < 4; ++j) {
                const int row = m0 + wr * 64 + mi * 16 + (lane >> 4) * 4 + j;
                const int col = n0 + wc * 64 + ni * 16 + (lane & 15);
                const float v = eluf(acc[mi][ni][j] + bias[col]);
                if (OUT_MODE == 1) {
                    ((_Float16*)Cout)[(size_t)(row >> 4) * 2048 + col * 16 + (row & 15)] = (_Float16)v;
                } else {
                    ((float*)Cout)[(size_t)row * N + col] = v;
                }
            }
}

// ---------------------------------------------------------------------------
extern "C" void kernel_launch(void* const* d_in, const int* in_sizes, int n_in,
                              void* d_out, int out_size, void* d_ws, size_t ws_size,
                              hipStream_t stream) {
    const float* x     = (const float*)d_in[0];
    const float* boxes = (const float*)d_in[1];
    const float* scale = (const float*)d_in[2];
    const float* w1    = (const float*)d_in[3];
    const float* b1    = (const float*)d_in[4];
    const float* w2    = (const float*)d_in[5];
    const float* b2    = (const float*)d_in[6];
    const float* wl    = (const float*)d_in[7];
    const float* bl    = (const float*)d_in[8];
    float* out = (float*)d_out;

    // workspace (fp16): z 16.8MB, h1 4.2MB, h2 2.1MB
    _Float16* z  = (_Float16*)d_ws;
    _Float16* h1 = z  + (size_t)MPIX * C1D;
    _Float16* h2 = h1 + (size_t)M1D * C1D;

    // 1) z = x @ w1^T  (channels-last, fp16)  [ROI-align commutes with 1x1 conv]
    conv1x1_f16<<<dim3(MPIX / 128, C1D / 128), dim3(256), 0, stream>>>(x, w1, z);

    // 2) h1 = elu(roi_align(z) + b1)   (8192 x 256 fp16)
    roi_gather_f16<<<dim3(R_ROI), dim3(256), 0, stream>>>(z, boxes, scale, b1, h1);

    // 3) h2 = elu(h1 @ w2^T + b2) scattered to (512 x 2048) fp16
    gemm_nt_f16<1><<<dim3(M1D / 128, C2D / 128), dim3(256), 0, stream>>>(
        h1, w2, b2, (void*)h2, M1D, C2D, C1D);

    // 4) out = elu(h2 @ wl^T + bl)   (512 x 2048 fp32)
    gemm_nt_f16<2><<<dim3(R_ROI / 128, OUTD / 128), dim3(256), 0, stream>>>(
        h2, wl, bl, (void*)out, R_ROI, OUTD, OUTD);
}

// Round 3
// 88.184 us; speedup vs baseline: 7.3283x; 1.3442x over previous
//
#include <hip/hip_runtime.h>
#include <math.h>

#define C_INK   1024
#define C1D     256
#define C2D     128
#define OUTD    2048
#define R_ROI   512
#define M1D     8192
#define MPIX    32768

typedef _Float16 half8 __attribute__((ext_vector_type(8)));
typedef float    f32x4 __attribute__((ext_vector_type(4)));

__device__ __forceinline__ unsigned int pack2h(float a, float b) {
    union { _Float16 h[2]; unsigned int u; } p;
    p.h[0] = (_Float16)a; p.h[1] = (_Float16)b;
    return p.u;
}
__device__ __forceinline__ float eluf(float v) { return v > 0.f ? v : expf(v) - 1.f; }

// XOR-swizzled LDS accessor: logical [row][chunk], chunk = 16B (8 halves).
// slot = chunk ^ (row & 7) spreads a column read/write across all 8 bank-groups.
__device__ __forceinline__ half8* ldsp(_Float16* base, int row, int ch) {
    return reinterpret_cast<half8*>(base) + row * 8 + (ch ^ (row & 7));
}

// ---------------------------------------------------------------------------
// Kernel 0: one-time fp32 -> fp16 conversion of w1, w2, wl
// ---------------------------------------------------------------------------
__global__ __launch_bounds__(256) void cvt_weights(
    const float* __restrict__ s1, _Float16* __restrict__ d1, int n1,
    const float* __restrict__ s2, _Float16* __restrict__ d2, int n2,
    const float* __restrict__ s3, _Float16* __restrict__ d3, int n3)
{
    int i = (blockIdx.x * 256 + threadIdx.x) * 4;
    const float* s; _Float16* d;
    if (i < n1)            { s = s1; d = d1; }
    else if (i < n1 + n2)  { s = s2; d = d2; i -= n1; }
    else                   { s = s3; d = d3; i -= n1 + n2; if (i >= n3) return; }
    const float4 v = *reinterpret_cast<const float4*>(s + i);
    uint2 u; u.x = pack2h(v.x, v.y); u.y = pack2h(v.z, v.w);
    *reinterpret_cast<uint2*>(d + i) = u;
}

// ---------------------------------------------------------------------------
// Kernel 1: conv1x1, z[pix][oc] = sum_k x[b][k][pix] * w1[oc][k]
// BM=128 (pixels), BN=256 (full C1), BK=64, 512 threads = 8 waves (2x4).
// x read exactly once (134 MB). Reg-staged pipeline hides HBM latency.
// ---------------------------------------------------------------------------
__global__ __launch_bounds__(512) void conv1x1_f16(
    const float* __restrict__ x, const _Float16* __restrict__ w1h,
    _Float16* __restrict__ z)
{
    __shared__ __align__(16) _Float16 As[128 * 64];
    __shared__ __align__(16) _Float16 Bs[256 * 64];

    const int tid  = threadIdx.x;
    const int lane = tid & 63;
    const int wave = tid >> 6;
    const int wr   = wave >> 2;          // 0..1  (64-row slice)
    const int wc   = wave & 3;           // 0..3  (64-col slice)
    const int m0   = blockIdx.x * 128;
    const int b    = m0 >> 12;
    const int p0   = m0 & 4095;

    // A-stage: wave k-group (8 k), lane = pixel; rows lane and lane+64
    const int akg = wave;
    // B-stage: lane-chunk mapping, rows r0+64i
    const int bc  = tid & 7;
    const int br0 = tid >> 3;            // 0..63

    float ar[16];
    half8 brg[4];
    f32x4 acc[4][4];
    #pragma unroll
    for (int i = 0; i < 4; ++i)
        #pragma unroll
        for (int j = 0; j < 4; ++j) acc[i][j] = (f32x4){0.f, 0.f, 0.f, 0.f};

    const float* xbase = x + (size_t)b * C_INK * 4096 + p0;

    auto LOADT = [&](int k0) {
        const float* xk = xbase + (size_t)(k0 + akg * 8) * 4096;
        #pragma unroll
        for (int j = 0; j < 8; ++j) {
            ar[j]     = xk[j * 4096 + lane];
            ar[8 + j] = xk[j * 4096 + lane + 64];
        }
        #pragma unroll
        for (int i = 0; i < 4; ++i)
            brg[i] = *reinterpret_cast<const half8*>(
                &w1h[(size_t)(br0 + i * 64) * C_INK + k0 + bc * 8]);
    };
    auto WRITET = [&]() {
        #pragma unroll
        for (int q = 0; q < 2; ++q) {
            union { half8 h; unsigned int u[4]; } pk;
            #pragma unroll
            for (int j = 0; j < 4; ++j) pk.u[j] = pack2h(ar[q * 8 + 2 * j], ar[q * 8 + 2 * j + 1]);
            *ldsp(As, lane + q * 64, akg) = pk.h;
        }
        #pragma unroll
        for (int i = 0; i < 4; ++i) *ldsp(Bs, br0 + i * 64, bc) = brg[i];
    };
    auto COMPUTET = [&]() {
        #pragma unroll
        for (int kk = 0; kk < 2; ++kk) {
            const int ch = kk * 4 + (lane >> 4);
            half8 af[4], bf[4];
            #pragma unroll
            for (int mi = 0; mi < 4; ++mi) af[mi] = *ldsp(As, wr * 64 + mi * 16 + (lane & 15), ch);
            #pragma unroll
            for (int ni = 0; ni < 4; ++ni) bf[ni] = *ldsp(Bs, wc * 64 + ni * 16 + (lane & 15), ch);
            #pragma unroll
            for (int mi = 0; mi < 4; ++mi)
                #pragma unroll
                for (int ni = 0; ni < 4; ++ni)
                    acc[mi][ni] = __builtin_amdgcn_mfma_f32_16x16x32_f16(af[mi], bf[ni], acc[mi][ni], 0, 0, 0);
        }
    };

    LOADT(0); WRITET(); __syncthreads();
    for (int t = 0; t < 15; ++t) {
        LOADT((t + 1) * 64);      // issue next tile's global loads early (T14)
        COMPUTET();               // MFMA on current tile hides the latency
        __syncthreads();
        WRITET();
        __syncthreads();
    }
    COMPUTET();

    _Float16* zp = z + (size_t)m0 * C1D;
    #pragma unroll
    for (int mi = 0; mi < 4; ++mi)
        #pragma unroll
        for (int ni = 0; ni < 4; ++ni)
            #pragma unroll
            for (int j = 0; j < 4; ++j) {
                const int row = wr * 64 + mi * 16 + (lane >> 4) * 4 + j;
                const int col = wc * 64 + ni * 16 + (lane & 15);
                zp[(size_t)row * C1D + col] = (_Float16)acc[mi][ni][j];
            }
}

// ---------------------------------------------------------------------------
// Kernel 2: ROI-align gather on z (channels-last fp16) + bias + ELU -> h1
// thread = (8-channel group, 2 cells): all gathers are half8 (16B) loads.
// ---------------------------------------------------------------------------
__global__ __launch_bounds__(256) void roi_gather_f16(
    const _Float16* __restrict__ z, const float* __restrict__ boxes,
    const float* __restrict__ scale_p, const float* __restrict__ b1,
    _Float16* __restrict__ h1)
{
    const int r   = blockIdx.x;
    const int tid = threadIdx.x;

    __shared__ int   s_off[64][4];
    __shared__ float s_w[64][4];

    if (tid < 64) {
        const float sc = scale_p[0];
        const float x1 = boxes[r * 4 + 0] * sc, y1 = boxes[r * 4 + 1] * sc;
        const float x2 = boxes[r * 4 + 2] * sc, y2 = boxes[r * 4 + 3] * sc;
        const float rw = fmaxf(x2 - x1, 1.f), rh = fmaxf(y2 - y1, 1.f);
        const int jy = tid >> 3, jx = tid & 7;

        float offy = (float)(jy >> 1) + (float)(jy & 1) * 0.5f + 0.25f;
        float cy = y1 + offy * rh * 0.25f;
        const bool vy = (cy >= -1.f) && (cy <= 64.f);
        cy = fminf(fmaxf(cy, 0.f), 63.f);
        int ylo = (int)cy; if (ylo > 63) ylo = 63;
        int yhi = ylo + 1; if (yhi > 63) yhi = 63;
        const float ly = cy - (float)ylo, hy = 1.f - ly;

        float offx = (float)(jx >> 1) + (float)(jx & 1) * 0.5f + 0.25f;
        float cx = x1 + offx * rw * 0.25f;
        const bool vx = (cx >= -1.f) && (cx <= 64.f);
        cx = fminf(fmaxf(cx, 0.f), 63.f);
        int xlo = (int)cx; if (xlo > 63) xlo = 63;
        int xhi = xlo + 1; if (xhi > 63) xhi = 63;
        const float lx = cx - (float)xlo, hx = 1.f - lx;

        const float wm = (vy && vx) ? 0.25f : 0.f;    // fold 2x2 mean
        s_w[tid][0] = hy * hx * wm;
        s_w[tid][1] = hy * lx * wm;
        s_w[tid][2] = ly * hx * wm;
        s_w[tid][3] = ly * lx * wm;
        s_off[tid][0] = (ylo * 64 + xlo) * C1D;
        s_off[tid][1] = (ylo * 64 + xhi) * C1D;
        s_off[tid][2] = (yhi * 64 + xlo) * C1D;
        s_off[tid][3] = (yhi * 64 + xhi) * C1D;
    }
    __syncthreads();

    const int ch8 = tid & 31;            // 8-channel group
    const int cg  = tid >> 5;            // 0..7 -> cells cg*2, cg*2+1
    const _Float16* zb = z + (size_t)(r >> 6) * 4096 * C1D + ch8 * 8;

    float bias[8];
    {
        const float4 b0 = *reinterpret_cast<const float4*>(&b1[ch8 * 8]);
        const float4 b4 = *reinterpret_cast<const float4*>(&b1[ch8 * 8 + 4]);
        bias[0] = b0.x; bias[1] = b0.y; bias[2] = b0.z; bias[3] = b0.w;
        bias[4] = b4.x; bias[5] = b4.y; bias[6] = b4.z; bias[7] = b4.w;
    }

    float accv[2][8];
    #pragma unroll
    for (int c = 0; c < 2; ++c)
        #pragma unroll
        for (int e = 0; e < 8; ++e) accv[c][e] = 0.f;

    #pragma unroll
    for (int cc = 0; cc < 2; ++cc) {
        const int cell = cg * 2 + cc;
        const int py = cell >> 2, px = cell & 3;
        #pragma unroll
        for (int u = 0; u < 4; ++u) {
            const int s = (py * 2 + (u >> 1)) * 8 + px * 2 + (u & 1);
            #pragma unroll
            for (int k = 0; k < 4; ++k) {
                const half8 v = *reinterpret_cast<const half8*>(zb + s_off[s][k]);
                const float w = s_w[s][k];
                #pragma unroll
                for (int e = 0; e < 8; ++e) accv[cc][e] += (float)v[e] * w;
            }
        }
    }

    #pragma unroll
    for (int cc = 0; cc < 2; ++cc) {
        const int row = r * 16 + cg * 2 + cc;
        half8 o;
        #pragma unroll
        for (int e = 0; e < 8; ++e) o[e] = (_Float16)eluf(accv[cc][e] + bias[e]);
        *reinterpret_cast<half8*>(&h1[(size_t)row * C1D + ch8 * 8]) = o;
    }
}

// ---------------------------------------------------------------------------
// Kernel 3: NT GEMM, fp16 A (MxK) x fp16 W (NxK), bias + ELU.
// BN=128 fixed, 256 threads = 4 waves (2x2). FM = fragments in M per wave.
// OUT_MODE 1: fp16 scatter h2[(m>>4)*2048 + n*16 + (m&15)]; 2: fp32 plain.
// ---------------------------------------------------------------------------
template<int BM, int FM, int OUT_MODE>
__global__ __launch_bounds__(256) void gemm_nt(
    const _Float16* __restrict__ A, const _Float16* __restrict__ W,
    const float* __restrict__ bias, void* __restrict__ Cout, int K, int N)
{
    constexpr int WM = FM * 16;
    constexpr int AI = BM / 32;
    __shared__ __align__(16) _Float16 As[BM * 64];
    __shared__ __align__(16) _Float16 Bs[128 * 64];

    const int tid  = threadIdx.x;
    const int lane = tid & 63;
    const int wave = tid >> 6;
    const int wr   = wave >> 1, wc = wave & 1;
    const int m0   = blockIdx.x * BM;
    const int n0   = blockIdx.y * 128;
    const int c    = tid & 7;
    const int r0   = tid >> 3;           // 0..31

    half8 arg[AI], brg[4];
    f32x4 acc[FM][4];
    #pragma unroll
    for (int i = 0; i < FM; ++i)
        #pragma unroll
        for (int j = 0; j < 4; ++j) acc[i][j] = (f32x4){0.f, 0.f, 0.f, 0.f};

    auto LOADT = [&](int k0) {
        #pragma unroll
        for (int i = 0; i < AI; ++i)
            arg[i] = *reinterpret_cast<const half8*>(&A[(size_t)(m0 + r0 + i * 32) * K + k0 + c * 8]);
        #pragma unroll
        for (int i = 0; i < 4; ++i)
            brg[i] = *reinterpret_cast<const half8*>(&W[(size_t)(n0 + r0 + i * 32) * K + k0 + c * 8]);
    };
    auto WRITET = [&]() {
        #pragma unroll
        for (int i = 0; i < AI; ++i) *ldsp(As, r0 + i * 32, c) = arg[i];
        #pragma unroll
        for (int i = 0; i < 4; ++i)  *ldsp(Bs, r0 + i * 32, c) = brg[i];
    };
    auto COMPUTET = [&]() {
        #pragma unroll
        for (int kk = 0; kk < 2; ++kk) {
            const int ch = kk * 4 + (lane >> 4);
            half8 af[FM], bf[4];
            #pragma unroll
            for (int mi = 0; mi < FM; ++mi) af[mi] = *ldsp(As, wr * WM + mi * 16 + (lane & 15), ch);
            #pragma unroll
            for (int ni = 0; ni < 4; ++ni)  bf[ni] = *ldsp(Bs, wc * 64 + ni * 16 + (lane & 15), ch);
            #pragma unroll
            for (int mi = 0; mi < FM; ++mi)
                #pragma unroll
                for (int ni = 0; ni < 4; ++ni)
                    acc[mi][ni] = __builtin_amdgcn_mfma_f32_16x16x32_f16(af[mi], bf[ni], acc[mi][ni], 0, 0, 0);
        }
    };

    const int nt = K / 64;
    LOADT(0); WRITET(); __syncthreads();
    for (int t = 0; t < nt - 1; ++t) {
        LOADT((t + 1) * 64);
        COMPUTET();
        __syncthreads();
        WRITET();
        __syncthreads();
    }
    COMPUTET();

    #pragma unroll
    for (int ni = 0; ni < 4; ++ni) {
        const int col = n0 + wc * 64 + ni * 16 + (lane & 15);
        const float bv = bias[col];
        #pragma unroll
        for (int mi = 0; mi < FM; ++mi)
            #pragma unroll
            for (int j = 0; j < 4; ++j) {
                const int row = m0 + wr * WM + mi * 16 + (lane >> 4) * 4 + j;
                const float v = eluf(acc[mi][ni][j] + bv);
                if (OUT_MODE == 1) {
                    ((_Float16*)Cout)[(size_t)(row >> 4) * 2048 + col * 16 + (row & 15)] = (_Float16)v;
                } else {
                    ((float*)Cout)[(size_t)row * N + col] = v;
                }
            }
    }
}

// ---------------------------------------------------------------------------
extern "C" void kernel_launch(void* const* d_in, const int* in_sizes, int n_in,
                              void* d_out, int out_size, void* d_ws, size_t ws_size,
                              hipStream_t stream) {
    const float* x     = (const float*)d_in[0];
    const float* boxes = (const float*)d_in[1];
    const float* scale = (const float*)d_in[2];
    const float* w1    = (const float*)d_in[3];
    const float* b1    = (const float*)d_in[4];
    const float* w2    = (const float*)d_in[5];
    const float* b2    = (const float*)d_in[6];
    const float* wl    = (const float*)d_in[7];
    const float* bl    = (const float*)d_in[8];
    float* out = (float*)d_out;

    // workspace layout (fp16 halves)
    _Float16* z   = (_Float16*)d_ws;                    // 32768 x 256
    _Float16* h1  = z   + (size_t)MPIX * C1D;           //  8192 x 256
    _Float16* h2  = h1  + (size_t)M1D * C1D;            //   512 x 2048
    _Float16* w1h = h2  + (size_t)R_ROI * OUTD;         //   256 x 1024
    _Float16* w2h = w1h + (size_t)C1D * C_INK;          //   128 x 256
    _Float16* wlh = w2h + (size_t)C2D * C1D;            //  2048 x 2048

    const int n1 = C1D * C_INK, n2 = C2D * C1D, n3 = OUTD * OUTD;

    // 0) weights -> fp16 (one pass)
    cvt_weights<<<dim3((n1 + n2 + n3) / 1024), dim3(256), 0, stream>>>(
        w1, w1h, n1, w2, w2h, n2, wl, wlh, n3);

    // 1) z = x @ w1^T (channels-last fp16); ROI-align commutes with 1x1 conv
    conv1x1_f16<<<dim3(MPIX / 128), dim3(512), 0, stream>>>(x, w1h, z);

    // 2) h1 = elu(roi_align(z) + b1)
    roi_gather_f16<<<dim3(R_ROI), dim3(256), 0, stream>>>(z, boxes, scale, b1, h1);

    // 3) h2 = elu(h1 @ w2^T + b2) scattered to (512 x 2048)
    gemm_nt<128, 4, 1><<<dim3(M1D / 128, 1), dim3(256), 0, stream>>>(
        h1, w2h, b2, (void*)h2, C1D, C2D);

    // 4) out = elu(h2 @ wl^T + bl)
    gemm_nt<64, 2, 2><<<dim3(R_ROI / 64, OUTD / 128), dim3(256), 0, stream>>>(
        h2, wlh, bl, (void*)out, OUTD, OUTD);
}

// Round 4
// 80.641 us; speedup vs baseline: 8.0138x; 1.0935x over previous
//
#include <hip/hip_runtime.h>
#include <math.h>

#define C_INK   1024
#define C1D     256
#define C2D     128
#define OUTD    2048
#define R_ROI   512
#define M1D     8192
#define MPIX    32768

typedef _Float16 half8 __attribute__((ext_vector_type(8)));
typedef float    f32x4 __attribute__((ext_vector_type(4)));

__device__ __forceinline__ unsigned int pack2h(float a, float b) {
    union { _Float16 h[2]; unsigned int u; } p;
    p.h[0] = (_Float16)a; p.h[1] = (_Float16)b;
    return p.u;
}
__device__ __forceinline__ float eluf(float v) { return v > 0.f ? v : expf(v) - 1.f; }

// XOR-swizzled LDS accessor: logical [row][chunk], chunk = 16B (8 halves),
// RC = chunks per row. slot = ch ^ (row&7) flips only the low 3 bits.
template<int RC>
__device__ __forceinline__ half8* ldsq(_Float16* base, int row, int ch) {
    return reinterpret_cast<half8*>(base) + row * RC + (ch ^ (row & 7));
}

// ---------------------------------------------------------------------------
// Kernel 0: one-time fp32 -> fp16 conversion of w1, w2, wl
// ---------------------------------------------------------------------------
__global__ __launch_bounds__(256) void cvt_weights(
    const float* __restrict__ s1, _Float16* __restrict__ d1, int n1,
    const float* __restrict__ s2, _Float16* __restrict__ d2, int n2,
    const float* __restrict__ s3, _Float16* __restrict__ d3, int n3)
{
    int i = (blockIdx.x * 256 + threadIdx.x) * 4;
    const float* s; _Float16* d;
    if (i < n1)            { s = s1; d = d1; }
    else if (i < n1 + n2)  { s = s2; d = d2; i -= n1; }
    else                   { s = s3; d = d3; i -= n1 + n2; if (i >= n3) return; }
    const float4 v = *reinterpret_cast<const float4*>(s + i);
    uint2 u; u.x = pack2h(v.x, v.y); u.y = pack2h(v.z, v.w);
    *reinterpret_cast<uint2*>(d + i) = u;
}

// ---------------------------------------------------------------------------
// Kernel 1: conv1x1, z[pix][oc] = sum_k x[b][k][pix] * w1[oc][k]
// BM=64 pixels, BN=256 (full C1 -> x read once), BK=64.
// 512 blocks x 512 threads (8 waves, wave = 64x32 output slice).
// LDS 40KB -> 2 blocks/CU resident, 4 waves/SIMD.
// ---------------------------------------------------------------------------
__global__ __launch_bounds__(512, 4) void conv1x1_f16(
    const float* __restrict__ x, const _Float16* __restrict__ w1h,
    _Float16* __restrict__ z)
{
    __shared__ __align__(16) _Float16 As[64 * 64];     //  8 KB [pixel][k]
    __shared__ __align__(16) _Float16 Bs[256 * 64];    // 32 KB [ochan][k]

    const int tid  = threadIdx.x;
    const int lane = tid & 63;
    const int wave = tid >> 6;          // 0..7
    const int m0   = blockIdx.x * 64;
    const int b    = m0 >> 12;
    const int p0   = m0 & 4095;

    // B-stage mapping: chunk c, rows r0 + 64i
    const int bc  = tid & 7;
    const int br0 = tid >> 3;           // 0..63

    float ar[8];
    half8 brg[4];
    f32x4 acc[4][2];
    #pragma unroll
    for (int i = 0; i < 4; ++i)
        #pragma unroll
        for (int j = 0; j < 2; ++j) acc[i][j] = (f32x4){0.f, 0.f, 0.f, 0.f};

    const float* xbase = x + (size_t)b * C_INK * 4096 + p0 + lane;

    auto LOADT = [&](int k0) {
        // A: wave w loads k-rows w*8..w*8+7 at pixel = lane (64 consecutive floats/instr)
        const float* xk = xbase + (size_t)(k0 + wave * 8) * 4096;
        #pragma unroll
        for (int j = 0; j < 8; ++j) ar[j] = xk[(size_t)j * 4096];
        #pragma unroll
        for (int i = 0; i < 4; ++i)
            brg[i] = *reinterpret_cast<const half8*>(
                &w1h[(size_t)(br0 + i * 64) * C_INK + k0 + bc * 8]);
    };
    auto WRITET = [&]() {
        union { half8 h; unsigned int u[4]; } pk;
        #pragma unroll
        for (int j = 0; j < 4; ++j) pk.u[j] = pack2h(ar[2 * j], ar[2 * j + 1]);
        *ldsq<8>(As, lane, wave) = pk.h;
        #pragma unroll
        for (int i = 0; i < 4; ++i) *ldsq<8>(Bs, br0 + i * 64, bc) = brg[i];
    };
    auto COMPUTET = [&]() {
        #pragma unroll
        for (int kk = 0; kk < 2; ++kk) {
            const int ch = kk * 4 + (lane >> 4);
            half8 af[4], bf[2];
            #pragma unroll
            for (int mi = 0; mi < 4; ++mi) af[mi] = *ldsq<8>(As, mi * 16 + (lane & 15), ch);
            #pragma unroll
            for (int ni = 0; ni < 2; ++ni) bf[ni] = *ldsq<8>(Bs, wave * 32 + ni * 16 + (lane & 15), ch);
            #pragma unroll
            for (int mi = 0; mi < 4; ++mi)
                #pragma unroll
                for (int ni = 0; ni < 2; ++ni)
                    acc[mi][ni] = __builtin_amdgcn_mfma_f32_16x16x32_f16(af[mi], bf[ni], acc[mi][ni], 0, 0, 0);
        }
    };

    LOADT(0); WRITET(); __syncthreads();
    for (int t = 0; t < 15; ++t) {
        LOADT((t + 1) * 64);      // issue next tile's global loads early
        COMPUTET();               // MFMA hides the latency
        __syncthreads();
        WRITET();
        __syncthreads();
    }
    COMPUTET();

    _Float16* zp = z + (size_t)m0 * C1D;
    #pragma unroll
    for (int mi = 0; mi < 4; ++mi)
        #pragma unroll
        for (int ni = 0; ni < 2; ++ni)
            #pragma unroll
            for (int j = 0; j < 4; ++j) {
                const int row = mi * 16 + (lane >> 4) * 4 + j;
                const int col = wave * 32 + ni * 16 + (lane & 15);
                zp[(size_t)row * C1D + col] = (_Float16)acc[mi][ni][j];
            }
}

// ---------------------------------------------------------------------------
// Kernel 2: fused ROI-align gather + bias/ELU + gemm2 (h1row @ w2^T) + bias/ELU
// One block per ROI (256 threads = 4 waves).
//   phase 0: stage w2 (128x256 fp16, 64KB) into LDS
//   phase 1: gather 16x256 h1-tile (half8 gathers from z) -> LDS
//   phase 2: MFMA 16x128x256, epilogue writes h2[r][o*16+p] contiguously
// ---------------------------------------------------------------------------
__global__ __launch_bounds__(256) void roi_gemm2_f16(
    const _Float16* __restrict__ z, const float* __restrict__ boxes,
    const float* __restrict__ scale_p, const float* __restrict__ b1v,
    const _Float16* __restrict__ w2h, const float* __restrict__ b2v,
    _Float16* __restrict__ h2)
{
    __shared__ __align__(16) _Float16 W2s[128 * 256];  // 64 KB
    __shared__ __align__(16) _Float16 H1s[16 * 256];   //  8 KB
    __shared__ int   s_off[64][4];
    __shared__ float s_w[64][4];

    const int r    = blockIdx.x;
    const int tid  = threadIdx.x;
    const int lane = tid & 63;

    // ---- ROI coefficients (threads 0..63) ----
    if (tid < 64) {
        const float sc = scale_p[0];
        const float x1 = boxes[r * 4 + 0] * sc, y1 = boxes[r * 4 + 1] * sc;
        const float x2 = boxes[r * 4 + 2] * sc, y2 = boxes[r * 4 + 3] * sc;
        const float rw = fmaxf(x2 - x1, 1.f), rh = fmaxf(y2 - y1, 1.f);
        const int jy = tid >> 3, jx = tid & 7;

        float offy = (float)(jy >> 1) + (float)(jy & 1) * 0.5f + 0.25f;
        float cy = y1 + offy * rh * 0.25f;
        const bool vy = (cy >= -1.f) && (cy <= 64.f);
        cy = fminf(fmaxf(cy, 0.f), 63.f);
        int ylo = (int)cy; if (ylo > 63) ylo = 63;
        int yhi = ylo + 1; if (yhi > 63) yhi = 63;
        const float ly = cy - (float)ylo, hy = 1.f - ly;

        float offx = (float)(jx >> 1) + (float)(jx & 1) * 0.5f + 0.25f;
        float cx = x1 + offx * rw * 0.25f;
        const bool vx = (cx >= -1.f) && (cx <= 64.f);
        cx = fminf(fmaxf(cx, 0.f), 63.f);
        int xlo = (int)cx; if (xlo > 63) xlo = 63;
        int xhi = xlo + 1; if (xhi > 63) xhi = 63;
        const float lx = cx - (float)xlo, hx = 1.f - lx;

        const float wm = (vy && vx) ? 0.25f : 0.f;     // fold 2x2 mean
        s_w[tid][0] = hy * hx * wm;
        s_w[tid][1] = hy * lx * wm;
        s_w[tid][2] = ly * hx * wm;
        s_w[tid][3] = ly * lx * wm;
        s_off[tid][0] = (ylo * 64 + xlo) * C1D;
        s_off[tid][1] = (ylo * 64 + xhi) * C1D;
        s_off[tid][2] = (yhi * 64 + xlo) * C1D;
        s_off[tid][3] = (yhi * 64 + xhi) * C1D;
    }

    // ---- stage w2 into LDS (row = tid>>1, 16 chunks each) ----
    {
        const int wr_ = tid >> 1;            // 0..127
        const int wcb = (tid & 1) * 16;      // chunk base 0 or 16
        #pragma unroll
        for (int bb = 0; bb < 4; ++bb) {
            half8 tmp[4];
            #pragma unroll
            for (int i = 0; i < 4; ++i)
                tmp[i] = *reinterpret_cast<const half8*>(&w2h[(size_t)wr_ * C1D + (wcb + bb * 4 + i) * 8]);
            #pragma unroll
            for (int i = 0; i < 4; ++i)
                *ldsq<32>(W2s, wr_, wcb + bb * 4 + i) = tmp[i];
        }
    }
    __syncthreads();

    // ---- gather phase: thread = (channel-octet ch8, cell-pair cg) ----
    {
        const int ch8 = tid & 31;
        const int cg  = tid >> 5;
        const _Float16* zb = z + (size_t)(r >> 6) * 4096 * C1D + ch8 * 8;

        float bias[8];
        {
            const float4 b0 = *reinterpret_cast<const float4*>(&b1v[ch8 * 8]);
            const float4 b4 = *reinterpret_cast<const float4*>(&b1v[ch8 * 8 + 4]);
            bias[0] = b0.x; bias[1] = b0.y; bias[2] = b0.z; bias[3] = b0.w;
            bias[4] = b4.x; bias[5] = b4.y; bias[6] = b4.z; bias[7] = b4.w;
        }

        float accv[2][8];
        #pragma unroll
        for (int c = 0; c < 2; ++c)
            #pragma unroll
            for (int e = 0; e < 8; ++e) accv[c][e] = 0.f;

        #pragma unroll
        for (int cc = 0; cc < 2; ++cc) {
            const int cell = cg * 2 + cc;
            const int py = cell >> 2, px = cell & 3;
            #pragma unroll
            for (int u = 0; u < 4; ++u) {
                const int s = (py * 2 + (u >> 1)) * 8 + px * 2 + (u & 1);
                #pragma unroll
                for (int k = 0; k < 4; ++k) {
                    const half8 v = *reinterpret_cast<const half8*>(zb + s_off[s][k]);
                    const float w = s_w[s][k];
                    #pragma unroll
                    for (int e = 0; e < 8; ++e) accv[cc][e] += (float)v[e] * w;
                }
            }
        }

        #pragma unroll
        for (int cc = 0; cc < 2; ++cc) {
            half8 o;
            #pragma unroll
            for (int e = 0; e < 8; ++e) o[e] = (_Float16)eluf(accv[cc][e] + bias[e]);
            *ldsq<32>(H1s, cg * 2 + cc, ch8) = o;
        }
    }
    __syncthreads();

    // ---- MFMA: C[16 x 128] = H1s @ W2s^T, K=256 ----
    {
        const int wv = tid >> 6;             // 0..3, n-frags wv*2, wv*2+1
        f32x4 o2[2];
        o2[0] = (f32x4){0.f, 0.f, 0.f, 0.f};
        o2[1] = (f32x4){0.f, 0.f, 0.f, 0.f};

        #pragma unroll
        for (int ks = 0; ks < 8; ++ks) {
            const int ch = ks * 4 + (lane >> 4);
            const half8 af = *ldsq<32>(H1s, lane & 15, ch);
            #pragma unroll
            for (int i = 0; i < 2; ++i) {
                const half8 bf = *ldsq<32>(W2s, (wv * 2 + i) * 16 + (lane & 15), ch);
                o2[i] = __builtin_amdgcn_mfma_f32_16x16x32_f16(af, bf, o2[i], 0, 0, 0);
            }
        }

        _Float16* hp = h2 + (size_t)r * 2048;
        #pragma unroll
        for (int i = 0; i < 2; ++i) {
            const int o = (wv * 2 + i) * 16 + (lane & 15);
            const float bv = b2v[o];
            #pragma unroll
            for (int j = 0; j < 4; ++j) {
                const int p = (lane >> 4) * 4 + j;
                hp[o * 16 + p] = (_Float16)eluf(o2[i][j] + bv);
            }
        }
    }
}

// ---------------------------------------------------------------------------
// Kernel 3: NT GEMM, fp16 A (MxK) x fp16 W (NxK), bias + ELU, fp32 out.
// BN=128, 256 threads = 4 waves (2x2). FM fragments in M per wave.
// ---------------------------------------------------------------------------
template<int BM, int FM>
__global__ __launch_bounds__(256) void gemm_nt(
    const _Float16* __restrict__ A, const _Float16* __restrict__ W,
    const float* __restrict__ bias, float* __restrict__ Cout, int K, int N)
{
    constexpr int WM = FM * 16;
    constexpr int AI = BM / 32;
    __shared__ __align__(16) _Float16 As[BM * 64];
    __shared__ __align__(16) _Float16 Bs[128 * 64];

    const int tid  = threadIdx.x;
    const int lane = tid & 63;
    const int wave = tid >> 6;
    const int wr   = wave >> 1, wc = wave & 1;
    const int m0   = blockIdx.x * BM;
    const int n0   = blockIdx.y * 128;
    const int c    = tid & 7;
    const int r0   = tid >> 3;           // 0..31

    half8 arg[AI], brg[4];
    f32x4 acc[FM][4];
    #pragma unroll
    for (int i = 0; i < FM; ++i)
        #pragma unroll
        for (int j = 0; j < 4; ++j) acc[i][j] = (f32x4){0.f, 0.f, 0.f, 0.f};

    auto LOADT = [&](int k0) {
        #pragma unroll
        for (int i = 0; i < AI; ++i)
            arg[i] = *reinterpret_cast<const half8*>(&A[(size_t)(m0 + r0 + i * 32) * K + k0 + c * 8]);
        #pragma unroll
        for (int i = 0; i < 4; ++i)
            brg[i] = *reinterpret_cast<const half8*>(&W[(size_t)(n0 + r0 + i * 32) * K + k0 + c * 8]);
    };
    auto WRITET = [&]() {
        #pragma unroll
        for (int i = 0; i < AI; ++i) *ldsq<8>(As, r0 + i * 32, c) = arg[i];
        #pragma unroll
        for (int i = 0; i < 4; ++i)  *ldsq<8>(Bs, r0 + i * 32, c) = brg[i];
    };
    auto COMPUTET = [&]() {
        #pragma unroll
        for (int kk = 0; kk < 2; ++kk) {
            const int ch = kk * 4 + (lane >> 4);
            half8 af[FM], bf[4];
            #pragma unroll
            for (int mi = 0; mi < FM; ++mi) af[mi] = *ldsq<8>(As, wr * WM + mi * 16 + (lane & 15), ch);
            #pragma unroll
            for (int ni = 0; ni < 4; ++ni)  bf[ni] = *ldsq<8>(Bs, wc * 64 + ni * 16 + (lane & 15), ch);
            #pragma unroll
            for (int mi = 0; mi < FM; ++mi)
                #pragma unroll
                for (int ni = 0; ni < 4; ++ni)
                    acc[mi][ni] = __builtin_amdgcn_mfma_f32_16x16x32_f16(af[mi], bf[ni], acc[mi][ni], 0, 0, 0);
        }
    };

    const int nt = K / 64;
    LOADT(0); WRITET(); __syncthreads();
    for (int t = 0; t < nt - 1; ++t) {
        LOADT((t + 1) * 64);
        COMPUTET();
        __syncthreads();
        WRITET();
        __syncthreads();
    }
    COMPUTET();

    #pragma unroll
    for (int ni = 0; ni < 4; ++ni) {
        const int col = n0 + wc * 64 + ni * 16 + (lane & 15);
        const float bv = bias[col];
        #pragma unroll
        for (int mi = 0; mi < FM; ++mi)
            #pragma unroll
            for (int j = 0; j < 4; ++j) {
                const int row = m0 + wr * WM + mi * 16 + (lane >> 4) * 4 + j;
                Cout[(size_t)row * N + col] = eluf(acc[mi][ni][j] + bv);
            }
    }
}

// ---------------------------------------------------------------------------
extern "C" void kernel_launch(void* const* d_in, const int* in_sizes, int n_in,
                              void* d_out, int out_size, void* d_ws, size_t ws_size,
                              hipStream_t stream) {
    const float* x     = (const float*)d_in[0];
    const float* boxes = (const float*)d_in[1];
    const float* scale = (const float*)d_in[2];
    const float* w1    = (const float*)d_in[3];
    const float* b1    = (const float*)d_in[4];
    const float* w2    = (const float*)d_in[5];
    const float* b2    = (const float*)d_in[6];
    const float* wl    = (const float*)d_in[7];
    const float* bl    = (const float*)d_in[8];
    float* out = (float*)d_out;

    // workspace layout (fp16 halves)
    _Float16* z   = (_Float16*)d_ws;                    // 32768 x 256
    _Float16* h2  = z   + (size_t)MPIX * C1D;           //   512 x 2048
    _Float16* w1h = h2  + (size_t)R_ROI * OUTD;         //   256 x 1024
    _Float16* w2h = w1h + (size_t)C1D * C_INK;          //   128 x 256
    _Float16* wlh = w2h + (size_t)C2D * C1D;            //  2048 x 2048

    const int n1 = C1D * C_INK, n2 = C2D * C1D, n3 = OUTD * OUTD;

    // 0) weights -> fp16
    cvt_weights<<<dim3((n1 + n2 + n3) / 1024), dim3(256), 0, stream>>>(
        w1, w1h, n1, w2, w2h, n2, wl, wlh, n3);

    // 1) z = x @ w1^T (channels-last fp16); ROI-align commutes with 1x1 conv
    conv1x1_f16<<<dim3(MPIX / 64), dim3(512), 0, stream>>>(x, w1h, z);

    // 2) h2 = elu( elu(roi_align(z)+b1) @ w2^T + b2 )  -- fused, one block/ROI
    roi_gemm2_f16<<<dim3(R_ROI), dim3(256), 0, stream>>>(
        z, boxes, scale, b1, w2h, b2, h2);

    // 3) out = elu(h2 @ wl^T + bl)
    gemm_nt<64, 2><<<dim3(R_ROI / 64, OUTD / 128), dim3(256), 0, stream>>>(
        h2, wlh, bl, out, OUTD, OUTD);
}

// Round 5
// 77.655 us; speedup vs baseline: 8.3220x; 1.0385x over previous
//
#include <hip/hip_runtime.h>
#include <math.h>

#define C_INK   1024
#define C1D     256
#define C2D     128
#define OUTD    2048
#define R_ROI   512
#define MPIX    32768

typedef _Float16 half8 __attribute__((ext_vector_type(8)));
typedef float    f32x4 __attribute__((ext_vector_type(4)));

__device__ __forceinline__ unsigned int pack2h(float a, float b) {
    union { _Float16 h[2]; unsigned int u; } p;
    p.h[0] = (_Float16)a; p.h[1] = (_Float16)b;
    return p.u;
}
__device__ __forceinline__ float eluf(float v) { return v > 0.f ? v : expf(v) - 1.f; }

// XOR-swizzled LDS accessor: logical [row][chunk], chunk = 16B (8 halves),
// RC = chunks per row. slot = ch ^ (row&7).
template<int RC>
__device__ __forceinline__ half8* ldsq(_Float16* base, int row, int ch) {
    return reinterpret_cast<half8*>(base) + row * RC + (ch ^ (row & 7));
}

// ---------------------------------------------------------------------------
// Kernel 0: one-time fp32 -> fp16 conversion of w1, w2, wl
// ---------------------------------------------------------------------------
__global__ __launch_bounds__(256) void cvt_weights(
    const float* __restrict__ s1, _Float16* __restrict__ d1, int n1,
    const float* __restrict__ s2, _Float16* __restrict__ d2, int n2,
    const float* __restrict__ s3, _Float16* __restrict__ d3, int n3)
{
    int i = (blockIdx.x * 256 + threadIdx.x) * 4;
    const float* s; _Float16* d;
    if (i < n1)            { s = s1; d = d1; }
    else if (i < n1 + n2)  { s = s2; d = d2; i -= n1; }
    else                   { s = s3; d = d3; i -= n1 + n2; if (i >= n3) return; }
    const float4 v = *reinterpret_cast<const float4*>(s + i);
    uint2 u; u.x = pack2h(v.x, v.y); u.y = pack2h(v.z, v.w);
    *reinterpret_cast<uint2*>(d + i) = u;
}

// ---------------------------------------------------------------------------
// Kernel 1: conv1x1, z[pix][oc] = sum_k x[b][k][pix] * w1[oc][k]
// BM=64 pixels, BN=256 (full C1 -> x read once), BK=64.
// 512 blocks x 512 threads (8 waves, wave = 64x32 output slice).
// MFMA operands swapped so epilogue packs 4 consecutive oc per lane (uint2).
// ---------------------------------------------------------------------------
__global__ __launch_bounds__(512, 4) void conv1x1_f16(
    const float* __restrict__ x, const _Float16* __restrict__ w1h,
    _Float16* __restrict__ z)
{
    __shared__ __align__(16) _Float16 As[64 * 64];     //  8 KB [pixel][k]
    __shared__ __align__(16) _Float16 Bs[256 * 64];    // 32 KB [ochan][k]

    const int tid  = threadIdx.x;
    const int lane = tid & 63;
    const int wave = tid >> 6;          // 0..7
    const int m0   = blockIdx.x * 64;
    const int b    = m0 >> 12;
    const int p0   = m0 & 4095;

    const int bc  = tid & 7;
    const int br0 = tid >> 3;           // 0..63

    float ar[8];
    half8 brg[4];
    f32x4 acc[4][2];
    #pragma unroll
    for (int i = 0; i < 4; ++i)
        #pragma unroll
        for (int j = 0; j < 2; ++j) acc[i][j] = (f32x4){0.f, 0.f, 0.f, 0.f};

    const float* xbase = x + (size_t)b * C_INK * 4096 + p0 + lane;

    auto LOADT = [&](int k0) {
        const float* xk = xbase + (size_t)(k0 + wave * 8) * 4096;
        #pragma unroll
        for (int j = 0; j < 8; ++j) ar[j] = xk[(size_t)j * 4096];
        #pragma unroll
        for (int i = 0; i < 4; ++i)
            brg[i] = *reinterpret_cast<const half8*>(
                &w1h[(size_t)(br0 + i * 64) * C_INK + k0 + bc * 8]);
    };
    auto WRITET = [&]() {
        union { half8 h; unsigned int u[4]; } pk;
        #pragma unroll
        for (int j = 0; j < 4; ++j) pk.u[j] = pack2h(ar[2 * j], ar[2 * j + 1]);
        *ldsq<8>(As, lane, wave) = pk.h;
        #pragma unroll
        for (int i = 0; i < 4; ++i) *ldsq<8>(Bs, br0 + i * 64, bc) = brg[i];
    };
    auto COMPUTET = [&]() {
        #pragma unroll
        for (int kk = 0; kk < 2; ++kk) {
            const int ch = kk * 4 + (lane >> 4);
            half8 af[4], bf[2];
            #pragma unroll
            for (int mi = 0; mi < 4; ++mi) af[mi] = *ldsq<8>(As, mi * 16 + (lane & 15), ch);
            #pragma unroll
            for (int ni = 0; ni < 2; ++ni) bf[ni] = *ldsq<8>(Bs, wave * 32 + ni * 16 + (lane & 15), ch);
            #pragma unroll
            for (int mi = 0; mi < 4; ++mi)
                #pragma unroll
                for (int ni = 0; ni < 2; ++ni)   // swapped: quad side = oc
                    acc[mi][ni] = __builtin_amdgcn_mfma_f32_16x16x32_f16(bf[ni], af[mi], acc[mi][ni], 0, 0, 0);
        }
    };

    LOADT(0); WRITET(); __syncthreads();
    for (int t = 0; t < 15; ++t) {
        LOADT((t + 1) * 64);      // issue next tile's global loads early
        COMPUTET();               // MFMA hides the latency
        __syncthreads();
        WRITET();
        __syncthreads();
    }
    COMPUTET();

    _Float16* zp = z + (size_t)m0 * C1D;
    #pragma unroll
    for (int mi = 0; mi < 4; ++mi) {
        const int pixel = mi * 16 + (lane & 15);
        #pragma unroll
        for (int ni = 0; ni < 2; ++ni) {
            const int oc0 = wave * 32 + ni * 16 + (lane >> 4) * 4;
            uint2 u;
            u.x = pack2h(acc[mi][ni][0], acc[mi][ni][1]);
            u.y = pack2h(acc[mi][ni][2], acc[mi][ni][3]);
            *reinterpret_cast<uint2*>(&zp[(size_t)pixel * C1D + oc0]) = u;
        }
    }
}

// ---------------------------------------------------------------------------
// Kernel 2: fused ROI-align gather + bias/ELU + gemm2 + bias/ELU -> h2 row.
// 512 threads, one block per ROI. w2 B-frags live in REGISTERS (prefetched at
// kernel top -> latency hides under coeff+gather). LDS = 16x256 H1 tile only.
// XCD-swizzled so each XCD's L2 caches exactly one image's z (2MB).
// ---------------------------------------------------------------------------
__global__ __launch_bounds__(512) void roi_gemm2_f16(
    const _Float16* __restrict__ z, const float* __restrict__ boxes,
    const float* __restrict__ scale_p, const float* __restrict__ b1v,
    const _Float16* __restrict__ w2h, const float* __restrict__ b2v,
    _Float16* __restrict__ h2)
{
    __shared__ __align__(16) _Float16 H1s[16 * 256];   // 8 KB, swizzled RC=32
    __shared__ int   s_off[64][4];
    __shared__ float s_w[64][4];

    const int bid  = blockIdx.x;
    const int r    = (bid & 7) * 64 + (bid >> 3);      // image i -> XCD i
    const int tid  = threadIdx.x;
    const int lane = tid & 63;
    const int wv   = tid >> 6;          // 0..7 -> output cols wv*16..wv*16+15

    // prefetch w2 B-fragments into registers (independent of gather)
    half8 bfr[8];
    {
        const _Float16* wp = w2h + (size_t)(wv * 16 + (lane & 15)) * C1D + (lane >> 4) * 8;
        #pragma unroll
        for (int ks = 0; ks < 8; ++ks)
            bfr[ks] = *reinterpret_cast<const half8*>(wp + ks * 32);
    }

    if (tid < 64) {
        const float sc = scale_p[0];
        const float x1 = boxes[r * 4 + 0] * sc, y1 = boxes[r * 4 + 1] * sc;
        const float x2 = boxes[r * 4 + 2] * sc, y2 = boxes[r * 4 + 3] * sc;
        const float rw = fmaxf(x2 - x1, 1.f), rh = fmaxf(y2 - y1, 1.f);
        const int jy = tid >> 3, jx = tid & 7;

        float offy = (float)(jy >> 1) + (float)(jy & 1) * 0.5f + 0.25f;
        float cy = y1 + offy * rh * 0.25f;
        const bool vy = (cy >= -1.f) && (cy <= 64.f);
        cy = fminf(fmaxf(cy, 0.f), 63.f);
        int ylo = (int)cy; if (ylo > 63) ylo = 63;
        int yhi = ylo + 1; if (yhi > 63) yhi = 63;
        const float ly = cy - (float)ylo, hy = 1.f - ly;

        float offx = (float)(jx >> 1) + (float)(jx & 1) * 0.5f + 0.25f;
        float cx = x1 + offx * rw * 0.25f;
        const bool vx = (cx >= -1.f) && (cx <= 64.f);
        cx = fminf(fmaxf(cx, 0.f), 63.f);
        int xlo = (int)cx; if (xlo > 63) xlo = 63;
        int xhi = xlo + 1; if (xhi > 63) xhi = 63;
        const float lx = cx - (float)xlo, hx = 1.f - lx;

        const float wm = (vy && vx) ? 0.25f : 0.f;     // fold 2x2 mean
        s_w[tid][0] = hy * hx * wm;
        s_w[tid][1] = hy * lx * wm;
        s_w[tid][2] = ly * hx * wm;
        s_w[tid][3] = ly * lx * wm;
        s_off[tid][0] = (ylo * 64 + xlo) * C1D;
        s_off[tid][1] = (ylo * 64 + xhi) * C1D;
        s_off[tid][2] = (yhi * 64 + xlo) * C1D;
        s_off[tid][3] = (yhi * 64 + xhi) * C1D;
    }
    __syncthreads();

    // gather: thread = (channel-octet ch8 = tid&31, cell = tid>>5)
    {
        const int ch8  = tid & 31;
        const int cell = tid >> 5;
        const _Float16* zb = z + (size_t)(r >> 6) * 4096 * C1D + ch8 * 8;

        float accv[8];
        #pragma unroll
        for (int e = 0; e < 8; ++e) accv[e] = 0.f;

        const int py = cell >> 2, px = cell & 3;
        #pragma unroll
        for (int u = 0; u < 4; ++u) {
            const int s = (py * 2 + (u >> 1)) * 8 + px * 2 + (u & 1);
            #pragma unroll
            for (int k = 0; k < 4; ++k) {
                const half8 v = *reinterpret_cast<const half8*>(zb + s_off[s][k]);
                const float w = s_w[s][k];
                #pragma unroll
                for (int e = 0; e < 8; ++e) accv[e] += (float)v[e] * w;
            }
        }

        const float4 b0 = *reinterpret_cast<const float4*>(&b1v[ch8 * 8]);
        const float4 b4 = *reinterpret_cast<const float4*>(&b1v[ch8 * 8 + 4]);
        half8 o;
        o[0] = (_Float16)eluf(accv[0] + b0.x); o[1] = (_Float16)eluf(accv[1] + b0.y);
        o[2] = (_Float16)eluf(accv[2] + b0.z); o[3] = (_Float16)eluf(accv[3] + b0.w);
        o[4] = (_Float16)eluf(accv[4] + b4.x); o[5] = (_Float16)eluf(accv[5] + b4.y);
        o[6] = (_Float16)eluf(accv[6] + b4.z); o[7] = (_Float16)eluf(accv[7] + b4.w);
        *ldsq<32>(H1s, cell, ch8) = o;
    }
    __syncthreads();

    // MFMA: wave wv computes C[16 cells x 16 cols], K=256
    f32x4 oa = (f32x4){0.f, 0.f, 0.f, 0.f};
    #pragma unroll
    for (int ks = 0; ks < 8; ++ks) {
        const int ch = ks * 4 + (lane >> 4);
        const half8 af = *ldsq<32>(H1s, lane & 15, ch);
        oa = __builtin_amdgcn_mfma_f32_16x16x32_f16(af, bfr[ks], oa, 0, 0, 0);
    }

    // epilogue: D cell = (lane>>4)*4+j (consecutive), col o = lane&15
    {
        const int o  = wv * 16 + (lane & 15);
        const int p0 = (lane >> 4) * 4;
        const float bv = b2v[o];
        uint2 u;
        u.x = pack2h(eluf(oa[0] + bv), eluf(oa[1] + bv));
        u.y = pack2h(eluf(oa[2] + bv), eluf(oa[3] + bv));
        *reinterpret_cast<uint2*>(&h2[(size_t)r * 2048 + o * 16 + p0]) = u;
    }
}

// ---------------------------------------------------------------------------
// Kernel 3: NT GEMM out = elu(h2 @ wl^T + bl), fp32 out.
// BM=64, BN=128, 512 threads (8 waves 2x4, wave = 32x32). Grid flat 128,
// XCD-swizzled decode. MFMA swapped -> float4 stores.
// ---------------------------------------------------------------------------
__global__ __launch_bounds__(512) void gemm_nt_out(
    const _Float16* __restrict__ A, const _Float16* __restrict__ W,
    const float* __restrict__ bias, float* __restrict__ Cout)
{
    constexpr int K = OUTD, N = OUTD;
    __shared__ __align__(16) _Float16 As[64 * 64];     //  8 KB
    __shared__ __align__(16) _Float16 Bs[128 * 64];    // 16 KB

    const int bid  = blockIdx.x;                 // 0..127
    const int xcd  = bid & 7;
    const int idx  = bid >> 3;                   // 0..15
    const int n0   = (xcd * 2 + (idx & 1)) * 128;
    const int m0   = (idx >> 1) * 64;

    const int tid  = threadIdx.x;
    const int lane = tid & 63;
    const int wave = tid >> 6;
    const int wr   = wave >> 2, wc = wave & 3;
    const int c    = tid & 7;
    const int r0   = tid >> 3;                   // 0..63

    half8 arg, brg[2];
    f32x4 acc[2][2];
    #pragma unroll
    for (int i = 0; i < 2; ++i)
        #pragma unroll
        for (int j = 0; j < 2; ++j) acc[i][j] = (f32x4){0.f, 0.f, 0.f, 0.f};

    auto LOADT = [&](int k0) {
        arg = *reinterpret_cast<const half8*>(&A[(size_t)(m0 + r0) * K + k0 + c * 8]);
        #pragma unroll
        for (int i = 0; i < 2; ++i)
            brg[i] = *reinterpret_cast<const half8*>(&W[(size_t)(n0 + r0 + i * 64) * K + k0 + c * 8]);
    };
    auto WRITET = [&]() {
        *ldsq<8>(As, r0, c) = arg;
        #pragma unroll
        for (int i = 0; i < 2; ++i) *ldsq<8>(Bs, r0 + i * 64, c) = brg[i];
    };
    auto COMPUTET = [&]() {
        #pragma unroll
        for (int kk = 0; kk < 2; ++kk) {
            const int ch = kk * 4 + (lane >> 4);
            half8 af[2], bf[2];
            #pragma unroll
            for (int mi = 0; mi < 2; ++mi) af[mi] = *ldsq<8>(As, wr * 32 + mi * 16 + (lane & 15), ch);
            #pragma unroll
            for (int ni = 0; ni < 2; ++ni) bf[ni] = *ldsq<8>(Bs, wc * 32 + ni * 16 + (lane & 15), ch);
            #pragma unroll
            for (int mi = 0; mi < 2; ++mi)
                #pragma unroll
                for (int ni = 0; ni < 2; ++ni)   // swapped: quad side = col
                    acc[mi][ni] = __builtin_amdgcn_mfma_f32_16x16x32_f16(bf[ni], af[mi], acc[mi][ni], 0, 0, 0);
        }
    };

    constexpr int nt = K / 64;
    LOADT(0); WRITET(); __syncthreads();
    for (int t = 0; t < nt - 1; ++t) {
        LOADT((t + 1) * 64);
        COMPUTET();
        __syncthreads();
        WRITET();
        __syncthreads();
    }
    COMPUTET();

    #pragma unroll
    for (int mi = 0; mi < 2; ++mi) {
        const int row = m0 + wr * 32 + mi * 16 + (lane & 15);
        #pragma unroll
        for (int ni = 0; ni < 2; ++ni) {
            const int col0 = n0 + wc * 32 + ni * 16 + (lane >> 4) * 4;
            const float4 bv = *reinterpret_cast<const float4*>(&bias[col0]);
            float4 o;
            o.x = eluf(acc[mi][ni][0] + bv.x);
            o.y = eluf(acc[mi][ni][1] + bv.y);
            o.z = eluf(acc[mi][ni][2] + bv.z);
            o.w = eluf(acc[mi][ni][3] + bv.w);
            *reinterpret_cast<float4*>(&Cout[(size_t)row * N + col0]) = o;
        }
    }
}

// ---------------------------------------------------------------------------
extern "C" void kernel_launch(void* const* d_in, const int* in_sizes, int n_in,
                              void* d_out, int out_size, void* d_ws, size_t ws_size,
                              hipStream_t stream) {
    const float* x     = (const float*)d_in[0];
    const float* boxes = (const float*)d_in[1];
    const float* scale = (const float*)d_in[2];
    const float* w1    = (const float*)d_in[3];
    const float* b1    = (const float*)d_in[4];
    const float* w2    = (const float*)d_in[5];
    const float* b2    = (const float*)d_in[6];
    const float* wl    = (const float*)d_in[7];
    const float* bl    = (const float*)d_in[8];
    float* out = (float*)d_out;

    // workspace layout (fp16 halves)
    _Float16* z   = (_Float16*)d_ws;                    // 32768 x 256
    _Float16* h2  = z   + (size_t)MPIX * C1D;           //   512 x 2048
    _Float16* w1h = h2  + (size_t)R_ROI * OUTD;         //   256 x 1024
    _Float16* w2h = w1h + (size_t)C1D * C_INK;          //   128 x 256
    _Float16* wlh = w2h + (size_t)C2D * C1D;            //  2048 x 2048

    const int n1 = C1D * C_INK, n2 = C2D * C1D, n3 = OUTD * OUTD;

    // 0) weights -> fp16
    cvt_weights<<<dim3((n1 + n2 + n3) / 1024), dim3(256), 0, stream>>>(
        w1, w1h, n1, w2, w2h, n2, wl, wlh, n3);

    // 1) z = x @ w1^T (channels-last fp16); ROI-align commutes with 1x1 conv
    conv1x1_f16<<<dim3(MPIX / 64), dim3(512), 0, stream>>>(x, w1h, z);

    // 2) h2 = elu( elu(roi_align(z)+b1) @ w2^T + b2 )  -- fused, one block/ROI
    roi_gemm2_f16<<<dim3(R_ROI), dim3(512), 0, stream>>>(
        z, boxes, scale, b1, w2h, b2, h2);

    // 3) out = elu(h2 @ wl^T + bl)
    gemm_nt_out<<<dim3(128), dim3(512), 0, stream>>>(h2, wlh, bl, out);
}